// Round 5
// baseline (314.066 us; speedup 1.0000x reference)
//
#include <hip/hip_runtime.h>
#include <hip/hip_cooperative_groups.h>

namespace cg = cooperative_groups;

// Problem constants (from reference setup_inputs): B=8, N=16384, K=64
#define BB 8
#define NN 16384
#define KK 64
#define NPG 512          // point groups (B*N / 256)

#if __has_builtin(__builtin_amdgcn_exp2f)
#define EXP2(x) __builtin_amdgcn_exp2f(x)
#else
#define EXP2(x) exp2f(x)
#endif

#define LOG2E 1.44269504088896340736f
// exp(inv*dist) = exp2( CW*dot + CE*(n2+1) ), inv = -12.5, ||w||^2 == 1
#define CW (25.0f * LOG2E)
#define CE (-12.5f * LOG2E)

// ---------------------------------------------------------------------------
// Kernel 0 (both paths): precompute scaled kernel directions into global SoA
// so hot loops read them with wave-uniform indices (s_load, no LDS traffic).
// ---------------------------------------------------------------------------
__global__ __launch_bounds__(256) void fkc_prep(
    const float* __restrict__ walpha, const float* __restrict__ wbeta,
    float* __restrict__ wx, float* __restrict__ wy, float* __restrict__ wz)
{
    const int t = threadIdx.x;
    float a = walpha[t];
    float b = wbeta[t];
    float sa = __sinf(a);
    wx[t] = CW * sa * __cosf(b);
    wy[t] = CW * sa * __sinf(b);
    wz[t] = CW * __cosf(a);
}

// ---------------------------------------------------------------------------
// Cooperative fused kernel: feats in registers -> grid-wide BN stats ->
// BN+ReLU write, single pass over out. Grid = 1024 (512 pg x 2 k-halves).
// __launch_bounds__(256,5): VGPR <= 102 -> >=5 blocks/CU -> coop limit 1280,
// comfortably above 1024 (R3's (256,4) was boundary-exact and got rejected).
// feat kept at 16x reference scale (BN is scale-invariant).
// ---------------------------------------------------------------------------
__global__ __launch_bounds__(256, 5) void fkc_fused(
    const float* __restrict__ normals,   // (B,3,N)
    const int*   __restrict__ nidx,      // (B,N,3) int32
    const float* __restrict__ wx, const float* __restrict__ wy,
    const float* __restrict__ wz,
    const float* __restrict__ gamma, const float* __restrict__ beta,
    float* __restrict__ out,             // (B,K,N)
    float* __restrict__ psum,            // [KK*NPG]
    float* __restrict__ pss,             // [KK*NPG]
    float* __restrict__ fin)             // [128]: scale[64], shift[64]
{
    cg::grid_group grid = cg::this_grid();

    __shared__ float reds[32][4];
    __shared__ float redss[32][4];
    __shared__ float fsc[KK], fsh[KK];

    const int tid = threadIdx.x;
    const int bid = blockIdx.x;
    const int pg = bid >> 1;             // point group 0..511
    const int k0 = (bid & 1) * 32;       // k half
    const int gid = pg * 256 + tid;
    const int b = gid >> 14;
    const int n = gid & (NN - 1);
    const float* nb = normals + b * 3 * NN;

    // Gather the 4 face points (center + 3 neighbors), all unit normals.
    float fx[4], fy[4], fz[4], e2[4];
    fx[0] = nb[n];
    fy[0] = nb[NN + n];
    fz[0] = nb[2 * NN + n];
    const int ibase = (b * NN + n) * 3;
#pragma unroll
    for (int j = 0; j < 3; ++j) {
        int id = nidx[ibase + j];
        fx[j + 1] = nb[id];
        fy[j + 1] = nb[NN + id];
        fz[j + 1] = nb[2 * NN + id];
    }
#pragma unroll
    for (int p = 0; p < 4; ++p) {
        float n2 = fmaf(fx[p], fx[p], fmaf(fy[p], fy[p], fz[p] * fz[p]));
        e2[p] = CE * (n2 + 1.0f);
    }

    // ---- Phase 1: 32 feats in registers + per-k (sum,sumsq) butterfly ----
    const int lane = tid & 63;
    const int wv = tid >> 6;
    float feats[32];
#pragma unroll 4
    for (int kk = 0; kk < 32; ++kk) {
        float acc = 0.0f;
#pragma unroll
        for (int m = 0; m < 4; ++m) {
            const int wi = ((k0 + kk) << 2) + m;   // scalar -> s_load
            float wxv = wx[wi], wyv = wy[wi], wzv = wz[wi];
#pragma unroll
            for (int p = 0; p < 4; ++p) {
                float arg = fmaf(fz[p], wzv,
                            fmaf(fy[p], wyv,
                            fmaf(fx[p], wxv, e2[p])));
                acc += EXP2(arg);
            }
        }
        feats[kk] = acc;
        float s = acc, ss = acc * acc;
#pragma unroll
        for (int off = 1; off < 64; off <<= 1) {
            s  += __shfl_xor(s,  off, 64);
            ss += __shfl_xor(ss, off, 64);
        }
        if (lane == 0) { reds[kk][wv] = s; redss[kk][wv] = ss; }
    }
    __syncthreads();
    if (tid < 32) {
        psum[(k0 + tid) * NPG + pg] =
            reds[tid][0] + reds[tid][1] + reds[tid][2] + reds[tid][3];
    } else if (tid < 64) {
        int kk = tid - 32;
        pss[(k0 + kk) * NPG + pg] =
            redss[kk][0] + redss[kk][1] + redss[kk][2] + redss[kk][3];
    }

    grid.sync();

    // ---- Phase 2: blocks 0..63 fold 512 partials -> scale/shift[k] ----
    if (bid < KK) {
        const int k = bid;
        float s  = psum[k * NPG + tid] + psum[k * NPG + 256 + tid];
        float ss = pss[k * NPG + tid]  + pss[k * NPG + 256 + tid];
#pragma unroll
        for (int off = 1; off < 64; off <<= 1) {
            s  += __shfl_xor(s,  off, 64);
            ss += __shfl_xor(ss, off, 64);
        }
        if (lane == 0) { reds[0][wv] = s; redss[0][wv] = ss; }
        __syncthreads();
        if (tid == 0) {
            float st  = reds[0][0] + reds[0][1] + reds[0][2] + reds[0][3];
            float sst = redss[0][0] + redss[0][1] + redss[0][2] + redss[0][3];
            const float invM = 1.0f / (float)(BB * NN);
            float mean = st * invM;
            float var = fmaf(-mean, mean, sst * invM);   // biased variance
            float sc = gamma[k] * rsqrtf(var + 1e-5f);
            fin[k] = sc;
            fin[KK + k] = fmaf(-mean, sc, beta[k]);
        }
    }

    grid.sync();

    // ---- Phase 3: BN + ReLU from registers, single global write ----
    if (tid < 2 * KK) {
        float v = fin[tid];              // vector-load path (L1 inv'd by sync)
        if (tid < KK) fsc[tid] = v; else fsh[tid - KK] = v;
    }
    __syncthreads();

    float* orow = out + (b * KK + k0) * NN + n;
#pragma unroll 4
    for (int kk = 0; kk < 32; ++kk) {
        float sc = fsc[k0 + kk];
        float sh = fsh[k0 + kk];
        orow[kk * NN] = fmaxf(fmaf(feats[kk], sc, sh), 0.0f);
    }
}

// ===========================================================================
// Fallback path (exactly the R4 kernels, proven passing at 118 us)
// ===========================================================================
__global__ __launch_bounds__(256, 8) void fkc_main(
    const float* __restrict__ normals, const int* __restrict__ nidx,
    const float* __restrict__ wx, const float* __restrict__ wy,
    const float* __restrict__ wz,
    float* __restrict__ out, float* __restrict__ psum, float* __restrict__ pss)
{
    __shared__ float reds[16][4];
    __shared__ float redss[16][4];

    const int tid = threadIdx.x;
    const int pg = blockIdx.x >> 2;
    const int k0 = (blockIdx.x & 3) * 16;
    const int gid = pg * 256 + tid;
    const int b = gid >> 14;
    const int n = gid & (NN - 1);
    const float* nb = normals + b * 3 * NN;

    float fx[4], fy[4], fz[4], e2[4];
    fx[0] = nb[n];
    fy[0] = nb[NN + n];
    fz[0] = nb[2 * NN + n];
    const int ibase = (b * NN + n) * 3;
#pragma unroll
    for (int j = 0; j < 3; ++j) {
        int id = nidx[ibase + j];
        fx[j + 1] = nb[id];
        fy[j + 1] = nb[NN + id];
        fz[j + 1] = nb[2 * NN + id];
    }
#pragma unroll
    for (int p = 0; p < 4; ++p) {
        float n2 = fmaf(fx[p], fx[p], fmaf(fy[p], fy[p], fz[p] * fz[p]));
        e2[p] = CE * (n2 + 1.0f);
    }

    const int lane = tid & 63;
    const int wv = tid >> 6;
    float* orow = out + (b * KK + k0) * NN + n;

#pragma unroll
    for (int kk = 0; kk < 16; ++kk) {
        float acc = 0.0f;
#pragma unroll
        for (int m = 0; m < 4; ++m) {
            const int wi = ((k0 + kk) << 2) + m;
            float wxv = wx[wi], wyv = wy[wi], wzv = wz[wi];
#pragma unroll
            for (int p = 0; p < 4; ++p) {
                float arg = fmaf(fz[p], wzv,
                            fmaf(fy[p], wyv,
                            fmaf(fx[p], wxv, e2[p])));
                acc += EXP2(arg);
            }
        }
        orow[kk * NN] = acc;
        float s = acc, ss = acc * acc;
#pragma unroll
        for (int off = 1; off < 64; off <<= 1) {
            s  += __shfl_xor(s,  off, 64);
            ss += __shfl_xor(ss, off, 64);
        }
        if (lane == 0) { reds[kk][wv] = s; redss[kk][wv] = ss; }
    }
    __syncthreads();

    if (tid < 16) {
        psum[(k0 + tid) * NPG + pg] =
            reds[tid][0] + reds[tid][1] + reds[tid][2] + reds[tid][3];
    } else if (tid < 32) {
        int kk = tid - 16;
        pss[(k0 + kk) * NPG + pg] =
            redss[kk][0] + redss[kk][1] + redss[kk][2] + redss[kk][3];
    }
}

__global__ __launch_bounds__(256) void fkc_stats(
    const float* __restrict__ psum, const float* __restrict__ pss,
    const float* __restrict__ gamma, const float* __restrict__ beta,
    float* __restrict__ fin)
{
    __shared__ float sw[4], ssw[4];
    const int tid = threadIdx.x;
    const int k = blockIdx.x;

    float s  = psum[k * NPG + tid] + psum[k * NPG + 256 + tid];
    float ss = pss[k * NPG + tid]  + pss[k * NPG + 256 + tid];
#pragma unroll
    for (int off = 1; off < 64; off <<= 1) {
        s  += __shfl_xor(s,  off, 64);
        ss += __shfl_xor(ss, off, 64);
    }
    const int wv = tid >> 6;
    if ((tid & 63) == 0) { sw[wv] = s; ssw[wv] = ss; }
    __syncthreads();
    if (tid == 0) {
        float st  = sw[0] + sw[1] + sw[2] + sw[3];
        float sst = ssw[0] + ssw[1] + ssw[2] + ssw[3];
        const float invM = 1.0f / (float)(BB * NN);
        float mean = st * invM;
        float var = fmaf(-mean, mean, sst * invM);
        float sc = gamma[k] * rsqrtf(var + 1e-5f);
        fin[k] = sc;
        fin[KK + k] = fmaf(-mean, sc, beta[k]);
    }
}

__global__ __launch_bounds__(256) void fkc_apply(
    float4* __restrict__ out4, const float* __restrict__ fin)
{
    const int i = blockIdx.x * 256 + threadIdx.x;
    const int k = (i >> 12) & (KK - 1);
    const float sc = fin[k];
    const float sh = fin[KK + k];
    float4 v = out4[i];
    v.x = fmaxf(fmaf(v.x, sc, sh), 0.0f);
    v.y = fmaxf(fmaf(v.y, sc, sh), 0.0f);
    v.z = fmaxf(fmaf(v.z, sc, sh), 0.0f);
    v.w = fmaxf(fmaf(v.w, sc, sh), 0.0f);
    out4[i] = v;
}

extern "C" void kernel_launch(void* const* d_in, const int* in_sizes, int n_in,
                              void* d_out, int out_size, void* d_ws, size_t ws_size,
                              hipStream_t stream) {
    const float* normals = (const float*)d_in[0];
    const int*   nidx    = (const int*)d_in[1];
    const float* walpha  = (const float*)d_in[2];
    const float* wbeta   = (const float*)d_in[3];
    const float* gamma   = (const float*)d_in[4];
    const float* beta    = (const float*)d_in[5];
    float* out = (float*)d_out;
    float* ws = (float*)d_ws;

    float* psum = ws;                        // [KK*NPG] = 32768 floats
    float* pss  = ws + KK * NPG;             // [KK*NPG]
    float* fin  = ws + 2 * KK * NPG;         // [128]
    float* wxb  = ws + 2 * KK * NPG + 128;   // [256]
    float* wyb  = wxb + 256;
    float* wzb  = wyb + 256;

    fkc_prep<<<1, 256, 0, stream>>>(walpha, wbeta, wxb, wyb, wzb);

    void* args[] = { &normals, &nidx, &wxb, &wyb, &wzb, &gamma, &beta,
                     &out, &psum, &pss, &fin };
    hipError_t err = hipLaunchCooperativeKernel((const void*)fkc_fused,
                                                dim3(1024), dim3(256),
                                                args, 0, stream);
    if (err != hipSuccess) {
        (void)hipGetLastError();   // clear sticky error for the harness
        // Fallback: proven 3-kernel path (R4).
        fkc_main<<<2048, 256, 0, stream>>>(normals, nidx, wxb, wyb, wzb,
                                           out, psum, pss);
        fkc_stats<<<KK, 256, 0, stream>>>(psum, pss, gamma, beta, fin);
        fkc_apply<<<8192, 256, 0, stream>>>((float4*)out, fin);
    }
}

// Round 6
// 290.655 us; speedup vs baseline: 1.0805x; 1.0805x over previous
//
#include <hip/hip_runtime.h>
#include <hip/hip_cooperative_groups.h>

namespace cg = cooperative_groups;

// Problem constants (from reference setup_inputs): B=8, N=16384, K=64
#define BB 8
#define NN 16384
#define KK 64
#define NPG 512          // point groups (B*N / 256)

#if __has_builtin(__builtin_amdgcn_exp2f)
#define EXP2(x) __builtin_amdgcn_exp2f(x)
#else
#define EXP2(x) exp2f(x)
#endif

#define LOG2E 1.44269504088896340736f
// exp(inv*dist) = exp2( CW*dot + CE*(n2+1) ), inv = -12.5, ||w||^2 == 1
#define CW (25.0f * LOG2E)
#define CE (-12.5f * LOG2E)

// ---------------------------------------------------------------------------
// Kernel 0 (both paths): precompute scaled kernel directions into global SoA
// so hot loops read them with uniform addresses (scalar-load path).
// ---------------------------------------------------------------------------
__global__ __launch_bounds__(256) void fkc_prep(
    const float* __restrict__ walpha, const float* __restrict__ wbeta,
    float* __restrict__ wx, float* __restrict__ wy, float* __restrict__ wz)
{
    const int t = threadIdx.x;
    float a = walpha[t];
    float b = wbeta[t];
    float sa = __sinf(a);
    wx[t] = CW * sa * __cosf(b);
    wy[t] = CW * sa * __sinf(b);
    wz[t] = CW * __cosf(a);
}

// ---------------------------------------------------------------------------
// Cooperative fused kernel: feats in registers -> grid-wide BN stats ->
// BN+ReLU write, single pass over out. Grid = 1024 (512 pg x 2 k-halves).
// (256,5): VGPR budget 102, 5 blocks/CU -> coop capacity 1280 > 1024
// (R5 proved this config launches). FULL unroll on the kk loops is
// mandatory: partial unroll dynamic-indexes feats[] -> scratch demotion
// (R5: VGPR=24, +33 MB scratch traffic, 229 us).
// feat kept at 16x reference scale (BN is scale-invariant).
// ---------------------------------------------------------------------------
__global__ __launch_bounds__(256, 5) void fkc_fused(
    const float* __restrict__ normals,   // (B,3,N)
    const int*   __restrict__ nidx,      // (B,N,3) int32
    const float* __restrict__ wx, const float* __restrict__ wy,
    const float* __restrict__ wz,
    const float* __restrict__ gamma, const float* __restrict__ beta,
    float* __restrict__ out,             // (B,K,N)
    float* __restrict__ psum,            // [KK*NPG]
    float* __restrict__ pss,             // [KK*NPG]
    float* __restrict__ fin)             // [128]: scale[64], shift[64]
{
    cg::grid_group grid = cg::this_grid();

    __shared__ float reds[32][4];
    __shared__ float redss[32][4];
    __shared__ float fsc[KK], fsh[KK];

    const int tid = threadIdx.x;
    const int bid = blockIdx.x;
    const int pg = bid >> 1;             // point group 0..511
    const int k0 = (bid & 1) * 32;       // k half
    const int gid = pg * 256 + tid;
    const int b = gid >> 14;
    const int n = gid & (NN - 1);
    const float* nb = normals + b * 3 * NN;

    // Gather the 4 face points (center + 3 neighbors), all unit normals.
    float fx[4], fy[4], fz[4], e2[4];
    fx[0] = nb[n];
    fy[0] = nb[NN + n];
    fz[0] = nb[2 * NN + n];
    const int ibase = (b * NN + n) * 3;
#pragma unroll
    for (int j = 0; j < 3; ++j) {
        int id = nidx[ibase + j];
        fx[j + 1] = nb[id];
        fy[j + 1] = nb[NN + id];
        fz[j + 1] = nb[2 * NN + id];
    }
#pragma unroll
    for (int p = 0; p < 4; ++p) {
        float n2 = fmaf(fx[p], fx[p], fmaf(fy[p], fy[p], fz[p] * fz[p]));
        e2[p] = CE * (n2 + 1.0f);
    }

    // ---- Phase 1: 32 feats in REGISTERS + per-k (sum,sumsq) butterfly ----
    const int lane = tid & 63;
    const int wv = tid >> 6;
    float feats[32];
#pragma unroll
    for (int kk = 0; kk < 32; ++kk) {
        float acc = 0.0f;
#pragma unroll
        for (int m = 0; m < 4; ++m) {
            const int wi = ((k0 + kk) << 2) + m;   // uniform address
            float wxv = wx[wi], wyv = wy[wi], wzv = wz[wi];
#pragma unroll
            for (int p = 0; p < 4; ++p) {
                float arg = fmaf(fz[p], wzv,
                            fmaf(fy[p], wyv,
                            fmaf(fx[p], wxv, e2[p])));
                acc += EXP2(arg);
            }
        }
        feats[kk] = acc;
        float s = acc, ss = acc * acc;
#pragma unroll
        for (int off = 1; off < 64; off <<= 1) {
            s  += __shfl_xor(s,  off, 64);
            ss += __shfl_xor(ss, off, 64);
        }
        if (lane == 0) { reds[kk][wv] = s; redss[kk][wv] = ss; }
    }
    __syncthreads();
    if (tid < 32) {
        psum[(k0 + tid) * NPG + pg] =
            reds[tid][0] + reds[tid][1] + reds[tid][2] + reds[tid][3];
    } else if (tid < 64) {
        int kk = tid - 32;
        pss[(k0 + kk) * NPG + pg] =
            redss[kk][0] + redss[kk][1] + redss[kk][2] + redss[kk][3];
    }

    grid.sync();

    // ---- Phase 2: blocks 0..63 fold 512 partials -> scale/shift[k] ----
    if (bid < KK) {
        const int k = bid;
        float s  = psum[k * NPG + tid] + psum[k * NPG + 256 + tid];
        float ss = pss[k * NPG + tid]  + pss[k * NPG + 256 + tid];
#pragma unroll
        for (int off = 1; off < 64; off <<= 1) {
            s  += __shfl_xor(s,  off, 64);
            ss += __shfl_xor(ss, off, 64);
        }
        if (lane == 0) { reds[0][wv] = s; redss[0][wv] = ss; }
        __syncthreads();
        if (tid == 0) {
            float st  = reds[0][0] + reds[0][1] + reds[0][2] + reds[0][3];
            float sst = redss[0][0] + redss[0][1] + redss[0][2] + redss[0][3];
            const float invM = 1.0f / (float)(BB * NN);
            float mean = st * invM;
            float var = fmaf(-mean, mean, sst * invM);   // biased variance
            float sc = gamma[k] * rsqrtf(var + 1e-5f);
            fin[k] = sc;
            fin[KK + k] = fmaf(-mean, sc, beta[k]);
        }
    }

    grid.sync();

    // ---- Phase 3: BN + ReLU from registers, single global write ----
    if (tid < 2 * KK) {
        float v = fin[tid];
        if (tid < KK) fsc[tid] = v; else fsh[tid - KK] = v;
    }
    __syncthreads();

    float* orow = out + (b * KK + k0) * NN + n;
#pragma unroll
    for (int kk = 0; kk < 32; ++kk) {
        float sc = fsc[k0 + kk];
        float sh = fsh[k0 + kk];
        orow[kk * NN] = fmaxf(fmaf(feats[kk], sc, sh), 0.0f);
    }
}

// ===========================================================================
// Fallback path (exactly the R4 kernels, proven passing at 118 us)
// ===========================================================================
__global__ __launch_bounds__(256, 8) void fkc_main(
    const float* __restrict__ normals, const int* __restrict__ nidx,
    const float* __restrict__ wx, const float* __restrict__ wy,
    const float* __restrict__ wz,
    float* __restrict__ out, float* __restrict__ psum, float* __restrict__ pss)
{
    __shared__ float reds[16][4];
    __shared__ float redss[16][4];

    const int tid = threadIdx.x;
    const int pg = blockIdx.x >> 2;
    const int k0 = (blockIdx.x & 3) * 16;
    const int gid = pg * 256 + tid;
    const int b = gid >> 14;
    const int n = gid & (NN - 1);
    const float* nb = normals + b * 3 * NN;

    float fx[4], fy[4], fz[4], e2[4];
    fx[0] = nb[n];
    fy[0] = nb[NN + n];
    fz[0] = nb[2 * NN + n];
    const int ibase = (b * NN + n) * 3;
#pragma unroll
    for (int j = 0; j < 3; ++j) {
        int id = nidx[ibase + j];
        fx[j + 1] = nb[id];
        fy[j + 1] = nb[NN + id];
        fz[j + 1] = nb[2 * NN + id];
    }
#pragma unroll
    for (int p = 0; p < 4; ++p) {
        float n2 = fmaf(fx[p], fx[p], fmaf(fy[p], fy[p], fz[p] * fz[p]));
        e2[p] = CE * (n2 + 1.0f);
    }

    const int lane = tid & 63;
    const int wv = tid >> 6;
    float* orow = out + (b * KK + k0) * NN + n;

#pragma unroll
    for (int kk = 0; kk < 16; ++kk) {
        float acc = 0.0f;
#pragma unroll
        for (int m = 0; m < 4; ++m) {
            const int wi = ((k0 + kk) << 2) + m;
            float wxv = wx[wi], wyv = wy[wi], wzv = wz[wi];
#pragma unroll
            for (int p = 0; p < 4; ++p) {
                float arg = fmaf(fz[p], wzv,
                            fmaf(fy[p], wyv,
                            fmaf(fx[p], wxv, e2[p])));
                acc += EXP2(arg);
            }
        }
        orow[kk * NN] = acc;
        float s = acc, ss = acc * acc;
#pragma unroll
        for (int off = 1; off < 64; off <<= 1) {
            s  += __shfl_xor(s,  off, 64);
            ss += __shfl_xor(ss, off, 64);
        }
        if (lane == 0) { reds[kk][wv] = s; redss[kk][wv] = ss; }
    }
    __syncthreads();

    if (tid < 16) {
        psum[(k0 + tid) * NPG + pg] =
            reds[tid][0] + reds[tid][1] + reds[tid][2] + reds[tid][3];
    } else if (tid < 32) {
        int kk = tid - 16;
        pss[(k0 + kk) * NPG + pg] =
            redss[kk][0] + redss[kk][1] + redss[kk][2] + redss[kk][3];
    }
}

__global__ __launch_bounds__(256) void fkc_stats(
    const float* __restrict__ psum, const float* __restrict__ pss,
    const float* __restrict__ gamma, const float* __restrict__ beta,
    float* __restrict__ fin)
{
    __shared__ float sw[4], ssw[4];
    const int tid = threadIdx.x;
    const int k = blockIdx.x;

    float s  = psum[k * NPG + tid] + psum[k * NPG + 256 + tid];
    float ss = pss[k * NPG + tid]  + pss[k * NPG + 256 + tid];
#pragma unroll
    for (int off = 1; off < 64; off <<= 1) {
        s  += __shfl_xor(s,  off, 64);
        ss += __shfl_xor(ss, off, 64);
    }
    const int wv = tid >> 6;
    if ((tid & 63) == 0) { sw[wv] = s; ssw[wv] = ss; }
    __syncthreads();
    if (tid == 0) {
        float st  = sw[0] + sw[1] + sw[2] + sw[3];
        float sst = ssw[0] + ssw[1] + ssw[2] + ssw[3];
        const float invM = 1.0f / (float)(BB * NN);
        float mean = st * invM;
        float var = fmaf(-mean, mean, sst * invM);
        float sc = gamma[k] * rsqrtf(var + 1e-5f);
        fin[k] = sc;
        fin[KK + k] = fmaf(-mean, sc, beta[k]);
    }
}

__global__ __launch_bounds__(256) void fkc_apply(
    float4* __restrict__ out4, const float* __restrict__ fin)
{
    const int i = blockIdx.x * 256 + threadIdx.x;
    const int k = (i >> 12) & (KK - 1);
    const float sc = fin[k];
    const float sh = fin[KK + k];
    float4 v = out4[i];
    v.x = fmaxf(fmaf(v.x, sc, sh), 0.0f);
    v.y = fmaxf(fmaf(v.y, sc, sh), 0.0f);
    v.z = fmaxf(fmaf(v.z, sc, sh), 0.0f);
    v.w = fmaxf(fmaf(v.w, sc, sh), 0.0f);
    out4[i] = v;
}

extern "C" void kernel_launch(void* const* d_in, const int* in_sizes, int n_in,
                              void* d_out, int out_size, void* d_ws, size_t ws_size,
                              hipStream_t stream) {
    const float* normals = (const float*)d_in[0];
    const int*   nidx    = (const int*)d_in[1];
    const float* walpha  = (const float*)d_in[2];
    const float* wbeta   = (const float*)d_in[3];
    const float* gamma   = (const float*)d_in[4];
    const float* beta    = (const float*)d_in[5];
    float* out = (float*)d_out;
    float* ws = (float*)d_ws;

    float* psum = ws;                        // [KK*NPG] = 32768 floats
    float* pss  = ws + KK * NPG;             // [KK*NPG]
    float* fin  = ws + 2 * KK * NPG;         // [128]
    float* wxb  = ws + 2 * KK * NPG + 128;   // [256]
    float* wyb  = wxb + 256;
    float* wzb  = wyb + 256;

    fkc_prep<<<1, 256, 0, stream>>>(walpha, wbeta, wxb, wyb, wzb);

    void* args[] = { &normals, &nidx, &wxb, &wyb, &wzb, &gamma, &beta,
                     &out, &psum, &pss, &fin };
    hipError_t err = hipLaunchCooperativeKernel((const void*)fkc_fused,
                                                dim3(1024), dim3(256),
                                                args, 0, stream);
    if (err != hipSuccess) {
        (void)hipGetLastError();   // clear sticky error for the harness
        // Fallback: proven 3-kernel path (R4).
        fkc_main<<<2048, 256, 0, stream>>>(normals, nidx, wxb, wyb, wzb,
                                           out, psum, pss);
        fkc_stats<<<KK, 256, 0, stream>>>(psum, pss, gamma, beta, fin);
        fkc_apply<<<8192, 256, 0, stream>>>((float4*)out, fin);
    }
}

// Round 7
// 116.643 us; speedup vs baseline: 2.6925x; 2.4918x over previous
//
#include <hip/hip_runtime.h>

// Problem constants (from reference setup_inputs): B=8, N=16384, K=64
#define BB 8
#define NN 16384
#define KK 64

#if __has_builtin(__builtin_amdgcn_exp2f)
#define EXP2(x) __builtin_amdgcn_exp2f(x)
#else
#define EXP2(x) exp2f(x)
#endif

#define LOG2E 1.44269504088896340736f
// exp(inv*dist) = exp2( CW*dot + CE*(n2+1) ), inv = -12.5, ||w||^2 == 1
#define CW (25.0f * LOG2E)
#define CE (-12.5f * LOG2E)

// ---------------------------------------------------------------------------
// Kernel 0: precompute scaled kernel directions into global SoA so the hot
// loop reads them with wave-uniform addresses (scalar-load path, zero VALU).
// ---------------------------------------------------------------------------
__global__ __launch_bounds__(256) void fkc_prep(
    const float* __restrict__ walpha, const float* __restrict__ wbeta,
    float* __restrict__ wx, float* __restrict__ wy, float* __restrict__ wz)
{
    const int t = threadIdx.x;
    float a = walpha[t];
    float b = wbeta[t];
    float sa = __sinf(a);
    wx[t] = CW * sa * __cosf(b);
    wy[t] = CW * sa * __sinf(b);
    wz[t] = CW * __cosf(a);
}

// ---------------------------------------------------------------------------
// Kernel 1: pure per-point feature compute + coalesced store. NO LDS, NO
// shuffles (R4's fused butterfly was ~192 DS-instr/thread on the one LDS
// pipe — a co-bottleneck with VALU). Grid = 2048 (512 pg x 4 k-quarters).
// feat kept at 16x reference scale (BN is scale-invariant).
// ---------------------------------------------------------------------------
__global__ __launch_bounds__(256, 8) void fkc_main(
    const float* __restrict__ normals,   // (B,3,N)
    const int*   __restrict__ nidx,      // (B,N,3) int32
    const float* __restrict__ wx, const float* __restrict__ wy,
    const float* __restrict__ wz,
    float* __restrict__ out)             // (B,K,N) feat (pre-BN, x16)
{
    const int tid = threadIdx.x;
    const int pg = blockIdx.x >> 2;          // point group 0..511
    const int k0 = (blockIdx.x & 3) * 16;    // k quarter
    const int gid = pg * 256 + tid;
    const int b = gid >> 14;
    const int n = gid & (NN - 1);
    const float* nb = normals + b * 3 * NN;

    // Gather the 4 face points (center + 3 neighbors), all unit normals.
    float fx[4], fy[4], fz[4], e2[4];
    fx[0] = nb[n];
    fy[0] = nb[NN + n];
    fz[0] = nb[2 * NN + n];
    const int ibase = (b * NN + n) * 3;
#pragma unroll
    for (int j = 0; j < 3; ++j) {
        int id = nidx[ibase + j];
        fx[j + 1] = nb[id];
        fy[j + 1] = nb[NN + id];
        fz[j + 1] = nb[2 * NN + id];
    }
#pragma unroll
    for (int p = 0; p < 4; ++p) {
        float n2 = fmaf(fx[p], fx[p], fmaf(fy[p], fy[p], fz[p] * fz[p]));
        e2[p] = CE * (n2 + 1.0f);
    }

    float* orow = out + (b * KK + k0) * NN + n;
#pragma unroll
    for (int kk = 0; kk < 16; ++kk) {
        float acc = 0.0f;
#pragma unroll
        for (int m = 0; m < 4; ++m) {
            const int wi = ((k0 + kk) << 2) + m;   // wave-uniform -> s_load
            float wxv = wx[wi], wyv = wy[wi], wzv = wz[wi];
#pragma unroll
            for (int p = 0; p < 4; ++p) {
                float arg = fmaf(fz[p], wzv,
                            fmaf(fy[p], wyv,
                            fmaf(fx[p], wxv, e2[p])));
                acc += EXP2(arg);
            }
        }
        orow[kk * NN] = acc;
    }
}

// ---------------------------------------------------------------------------
// Kernel 2: per-k (sum, sumsq) partials from the (L2/L3-resident) out.
// 256 blocks: block r -> k = r>>2, chunk c = r&3 covering b in {2c, 2c+1}.
// Each thread reads 32 float4 (two 16384-elem rows / 256 threads).
// ---------------------------------------------------------------------------
__global__ __launch_bounds__(256) void fkc_reduce(
    const float4* __restrict__ out4,
    float* __restrict__ psum,            // [KK*4]
    float* __restrict__ pss)             // [KK*4]
{
    __shared__ float sw[4], ssw[4];
    const int tid = threadIdx.x;
    const int k = blockIdx.x >> 2;
    const int c = blockIdx.x & 3;

    float s = 0.0f, ss = 0.0f;
#pragma unroll
    for (int r = 0; r < 2; ++r) {
        const int b = 2 * c + r;
        const int base4 = (b * KK + k) * (NN / 4);
#pragma unroll
        for (int j = 0; j < 16; ++j) {
            float4 v = out4[base4 + tid + j * 256];
            s += (v.x + v.y) + (v.z + v.w);
            ss += fmaf(v.x, v.x, fmaf(v.y, v.y, fmaf(v.z, v.z, v.w * v.w)));
        }
    }
#pragma unroll
    for (int off = 1; off < 64; off <<= 1) {
        s  += __shfl_xor(s,  off, 64);
        ss += __shfl_xor(ss, off, 64);
    }
    const int wv = tid >> 6;
    if ((tid & 63) == 0) { sw[wv] = s; ssw[wv] = ss; }
    __syncthreads();
    if (tid == 0) {
        psum[k * 4 + c] = sw[0] + sw[1] + sw[2] + sw[3];
        pss[k * 4 + c]  = ssw[0] + ssw[1] + ssw[2] + ssw[3];
    }
}

// ---------------------------------------------------------------------------
// Kernel 3: BN + ReLU in place, float4. k uniform per block; each block folds
// the 4 partials inline (8 wave-uniform loads -> scalar path, ~no cost).
// ---------------------------------------------------------------------------
__global__ __launch_bounds__(256) void fkc_apply(
    float4* __restrict__ out4,
    const float* __restrict__ psum,
    const float* __restrict__ pss,
    const float* __restrict__ gamma,
    const float* __restrict__ beta)
{
    const int i = blockIdx.x * 256 + threadIdx.x;
    const int k = (i >> 12) & (KK - 1);      // uniform within block

    float st  = (psum[k * 4 + 0] + psum[k * 4 + 1]) +
                (psum[k * 4 + 2] + psum[k * 4 + 3]);
    float sst = (pss[k * 4 + 0] + pss[k * 4 + 1]) +
                (pss[k * 4 + 2] + pss[k * 4 + 3]);
    const float invM = 1.0f / (float)(BB * NN);
    float mean = st * invM;
    float var = fmaf(-mean, mean, sst * invM);   // biased variance
    float sc = gamma[k] * rsqrtf(var + 1e-5f);
    float sh = fmaf(-mean, sc, beta[k]);

    float4 v = out4[i];
    v.x = fmaxf(fmaf(v.x, sc, sh), 0.0f);
    v.y = fmaxf(fmaf(v.y, sc, sh), 0.0f);
    v.z = fmaxf(fmaf(v.z, sc, sh), 0.0f);
    v.w = fmaxf(fmaf(v.w, sc, sh), 0.0f);
    out4[i] = v;
}

extern "C" void kernel_launch(void* const* d_in, const int* in_sizes, int n_in,
                              void* d_out, int out_size, void* d_ws, size_t ws_size,
                              hipStream_t stream) {
    const float* normals = (const float*)d_in[0];
    const int*   nidx    = (const int*)d_in[1];
    const float* walpha  = (const float*)d_in[2];
    const float* wbeta   = (const float*)d_in[3];
    const float* gamma   = (const float*)d_in[4];
    const float* beta    = (const float*)d_in[5];
    float* out = (float*)d_out;
    float* ws = (float*)d_ws;

    float* psum = ws;            // [256]
    float* pss  = ws + 256;      // [256]
    float* wxb  = ws + 512;      // [256]
    float* wyb  = ws + 768;      // [256]
    float* wzb  = ws + 1024;     // [256]

    fkc_prep<<<1, 256, 0, stream>>>(walpha, wbeta, wxb, wyb, wzb);
    fkc_main<<<2048, 256, 0, stream>>>(normals, nidx, wxb, wyb, wzb, out);
    fkc_reduce<<<256, 256, 0, stream>>>((const float4*)out, psum, pss);
    fkc_apply<<<8192, 256, 0, stream>>>((float4*)out, psum, pss, gamma, beta);
}

// Round 8
// 111.562 us; speedup vs baseline: 2.8152x; 1.0455x over previous
//
#include <hip/hip_runtime.h>

// Problem constants (from reference setup_inputs): B=8, N=16384, K=64
#define BB 8
#define NN 16384
#define KK 64

#if __has_builtin(__builtin_amdgcn_exp2f)
#define EXP2(x) __builtin_amdgcn_exp2f(x)
#else
#define EXP2(x) exp2f(x)
#endif

typedef float v2f __attribute__((ext_vector_type(2)));

#if __has_builtin(__builtin_elementwise_fma)
#define FMA2(a, b, c) __builtin_elementwise_fma((a), (b), (c))
#else
static __device__ inline v2f FMA2(v2f a, v2f b, v2f c) {
    v2f r; r.x = fmaf(a.x, b.x, c.x); r.y = fmaf(a.y, b.y, c.y); return r;
}
#endif

#define LOG2E 1.44269504088896340736f
// exp(inv*dist) = exp2( CW*dot + CE*(n2+1) ), inv = -12.5, ||w||^2 == 1
#define CW (25.0f * LOG2E)
#define CE (-12.5f * LOG2E)

// ---------------------------------------------------------------------------
// Kernel 0: precompute scaled kernel directions into global SoA so the hot
// loop reads them with wave-uniform addresses (scalar-load path, zero VALU).
// ---------------------------------------------------------------------------
__global__ __launch_bounds__(256) void fkc_prep(
    const float* __restrict__ walpha, const float* __restrict__ wbeta,
    float* __restrict__ wx, float* __restrict__ wy, float* __restrict__ wz)
{
    const int t = threadIdx.x;
    float a = walpha[t];
    float b = wbeta[t];
    float sa = __sinf(a);
    wx[t] = CW * sa * __cosf(b);
    wy[t] = CW * sa * __sinf(b);
    wz[t] = CW * __cosf(a);
}

// ---------------------------------------------------------------------------
// Kernel 1: per-point feature compute (packed-FP32 dot products) + coalesced
// store + LDS-staged per-k (sum,sumsq) reduction + 2 atomicAdds per k.
// NO butterfly shuffles (they hammer the same LDS pipe: 192 ops vs ~36 here).
// Grid = 2048 (512 pg x 4 k-quarters). feat kept at 16x reference scale.
// LDS: 16x257 stage (pad 257: write bank (kk+tid)%32 and read bank
// (k+16*part+r)%32 are both 2-way over 64 lanes = free per m136).
// ---------------------------------------------------------------------------
__global__ __launch_bounds__(256, 8) void fkc_main(
    const float* __restrict__ normals,   // (B,3,N)
    const int*   __restrict__ nidx,      // (B,N,3) int32
    const float* __restrict__ wx, const float* __restrict__ wy,
    const float* __restrict__ wz,
    float* __restrict__ out,             // (B,K,N) feat (pre-BN, x16)
    float* __restrict__ gsum,            // [KK] zero-init'd, atomic
    float* __restrict__ gss)             // [KK]
{
    __shared__ float fl[16][257];        // feats stage, 16.4 KB
    __shared__ float ps[16][17], pq[16][17];

    const int tid = threadIdx.x;
    const int pg = blockIdx.x >> 2;          // point group 0..511
    const int k0 = (blockIdx.x & 3) * 16;    // k quarter
    const int gid = pg * 256 + tid;
    const int b = gid >> 14;
    const int n = gid & (NN - 1);
    const float* nb = normals + b * 3 * NN;

    // Gather the 4 face points (center + 3 neighbors), all unit normals.
    float fx[4], fy[4], fz[4];
    fx[0] = nb[n];
    fy[0] = nb[NN + n];
    fz[0] = nb[2 * NN + n];
    const int ibase = (b * NN + n) * 3;
#pragma unroll
    for (int j = 0; j < 3; ++j) {
        int id = nidx[ibase + j];
        fx[j + 1] = nb[id];
        fy[j + 1] = nb[NN + id];
        fz[j + 1] = nb[2 * NN + id];
    }

    // Pack p-pairs for v_pk_fma_f32.
    v2f fx01 = {fx[0], fx[1]}, fx23 = {fx[2], fx[3]};
    v2f fy01 = {fy[0], fy[1]}, fy23 = {fy[2], fy[3]};
    v2f fz01 = {fz[0], fz[1]}, fz23 = {fz[2], fz[3]};
    v2f e01, e23;
    {
        v2f n2a = FMA2(fx01, fx01, FMA2(fy01, fy01, fz01 * fz01));
        v2f n2b = FMA2(fx23, fx23, FMA2(fy23, fy23, fz23 * fz23));
        e01 = CE * (n2a + 1.0f);
        e23 = CE * (n2b + 1.0f);
    }

    float* orow = out + (b * KK + k0) * NN + n;
#pragma unroll
    for (int kk = 0; kk < 16; ++kk) {
        v2f acc01 = {0.0f, 0.0f}, acc23 = {0.0f, 0.0f};
#pragma unroll
        for (int m = 0; m < 4; ++m) {
            const int wi = ((k0 + kk) << 2) + m;   // wave-uniform -> s_load
            float wxv = wx[wi], wyv = wy[wi], wzv = wz[wi];
            v2f wx2 = {wxv, wxv}, wy2 = {wyv, wyv}, wz2 = {wzv, wzv};
            v2f a01 = FMA2(fz01, wz2, FMA2(fy01, wy2, FMA2(fx01, wx2, e01)));
            v2f a23 = FMA2(fz23, wz2, FMA2(fy23, wy2, FMA2(fx23, wx2, e23)));
            v2f x01 = {EXP2(a01.x), EXP2(a01.y)};
            v2f x23 = {EXP2(a23.x), EXP2(a23.y)};
            acc01 += x01;
            acc23 += x23;
        }
        v2f t2 = acc01 + acc23;
        float acc = t2.x + t2.y;
        orow[kk * NN] = acc;
        fl[kk][tid] = acc;
    }
    __syncthreads();

    // Column-sum the stage: thread (k = tid&15, part = tid>>4) sums 16 feats.
    {
        const int k = tid & 15;
        const int part = tid >> 4;
        float s = 0.0f, ss = 0.0f;
#pragma unroll
        for (int r = 0; r < 16; ++r) {
            float v = fl[k][part * 16 + r];
            s += v;
            ss = fmaf(v, v, ss);
        }
        ps[k][part] = s;
        pq[k][part] = ss;
    }
    __syncthreads();

    if (tid < 16) {
        float s = 0.0f;
#pragma unroll
        for (int r = 0; r < 16; ++r) s += ps[tid][r];
        atomicAdd(&gsum[k0 + tid], s);
    } else if (tid < 32) {
        const int kk = tid - 16;
        float ss = 0.0f;
#pragma unroll
        for (int r = 0; r < 16; ++r) ss += pq[kk][r];
        atomicAdd(&gss[k0 + kk], ss);
    }
}

// ---------------------------------------------------------------------------
// Kernel 2: BN + ReLU in place, float4. k uniform per block -> gsum/gss/
// gamma/beta all scalar loads; mean/var recomputed per block (trivial).
// ---------------------------------------------------------------------------
__global__ __launch_bounds__(256) void fkc_apply(
    float4* __restrict__ out4,
    const float* __restrict__ gsum,
    const float* __restrict__ gss,
    const float* __restrict__ gamma,
    const float* __restrict__ beta)
{
    const int i = blockIdx.x * 256 + threadIdx.x;
    const int k = (i >> 12) & (KK - 1);      // uniform within block

    const float invM = 1.0f / (float)(BB * NN);
    float mean = gsum[k] * invM;
    float var = fmaf(-mean, mean, gss[k] * invM);   // biased variance
    float sc = gamma[k] * rsqrtf(var + 1e-5f);
    float sh = fmaf(-mean, sc, beta[k]);

    float4 v = out4[i];
    v.x = fmaxf(fmaf(v.x, sc, sh), 0.0f);
    v.y = fmaxf(fmaf(v.y, sc, sh), 0.0f);
    v.z = fmaxf(fmaf(v.z, sc, sh), 0.0f);
    v.w = fmaxf(fmaf(v.w, sc, sh), 0.0f);
    out4[i] = v;
}

extern "C" void kernel_launch(void* const* d_in, const int* in_sizes, int n_in,
                              void* d_out, int out_size, void* d_ws, size_t ws_size,
                              hipStream_t stream) {
    const float* normals = (const float*)d_in[0];
    const int*   nidx    = (const int*)d_in[1];
    const float* walpha  = (const float*)d_in[2];
    const float* wbeta   = (const float*)d_in[3];
    const float* gamma   = (const float*)d_in[4];
    const float* beta    = (const float*)d_in[5];
    float* out = (float*)d_out;
    float* ws = (float*)d_ws;

    float* gsum = ws;            // [64]  (atomic accumulators)
    float* gss  = ws + 64;       // [64]
    float* wxb  = ws + 128;      // [256]
    float* wyb  = ws + 384;      // [256]
    float* wzb  = ws + 640;      // [256]

    // ws is re-poisoned 0xAA before every timed launch -> zero the atomics.
    hipMemsetAsync(ws, 0, 128 * sizeof(float), stream);

    fkc_prep<<<1, 256, 0, stream>>>(walpha, wbeta, wxb, wyb, wzb);
    fkc_main<<<2048, 256, 0, stream>>>(normals, nidx, wxb, wyb, wzb,
                                       out, gsum, gss);
    fkc_apply<<<8192, 256, 0, stream>>>((float4*)out, gsum, gss, gamma, beta);
}